// Round 1
// baseline (1182.713 us; speedup 1.0000x reference)
//
#include <hip/hip_runtime.h>

#define D 128

// ---------------------------------------------------------------------------
// Scatter: agg[dst] += H[src] over edges; deg[dst] += 1.
// 32 lanes per edge, float4 per lane (512 B contiguous gather per edge).
// unsafeAtomicAdd => native global_atomic_add_f32 (no CAS loop).
// ---------------------------------------------------------------------------
__global__ __launch_bounds__(256) void scatter_kernel(
    const float* __restrict__ H, const int* __restrict__ esrc,
    const int* __restrict__ edst, float* __restrict__ agg,
    float* __restrict__ deg, int E)
{
    int e = blockIdx.x * 8 + (threadIdx.x >> 5);
    if (e >= E) return;
    int lane = threadIdx.x & 31;
    int src = esrc[e];
    int dst = edst[e];
    const float4* hv = (const float4*)(H + (size_t)src * D);
    float4 v = hv[lane];
    float* a = agg + (size_t)dst * D + lane * 4;
    unsafeAtomicAdd(a + 0, v.x);
    unsafeAtomicAdd(a + 1, v.y);
    unsafeAtomicAdd(a + 2, v.z);
    unsafeAtomicAdd(a + 3, v.w);
    if (lane == 0) unsafeAtomicAdd(deg + dst, 1.0f);
}

// ---------------------------------------------------------------------------
// out = relu( (agg @ W) / max(deg,1) + (deg>0 ? b : 0) ), in-place on agg.
// Block handles 16 rows. A staged fully in LDS before any write (in-place
// safe: rows are block-exclusive). W staged in two 64-row LDS passes.
// LDS = 32KB (W half) + 8KB (A) = 40KB -> 4 blocks/CU.
// ---------------------------------------------------------------------------
__global__ __launch_bounds__(256) void gemm_finalize_kernel(
    float* __restrict__ out,            // in: agg, out: result (in-place)
    const float* __restrict__ W,        // [128,128] row-major
    const float* __restrict__ b,        // [128]
    const float* __restrict__ deg,      // [n_dst]
    int n_dst)
{
    __shared__ float Wl[64][D];   // 32 KB: half of W (64 k-rows)
    __shared__ float Al[16][D];   // 8 KB: 16 A rows

    const int tid  = threadIdx.x;
    const int row0 = blockIdx.x * 16;

    // Stage A rows (float4 vectorized), zero-fill out-of-range rows.
    {
        const float4* src  = (const float4*)(out + (size_t)row0 * D);
        float4*       dstl = (float4*)&Al[0][0];
        int maxv = (n_dst - row0) * (D / 4);           // valid float4 count
        if (maxv > 16 * (D / 4)) maxv = 16 * (D / 4);
        for (int i = tid; i < 16 * (D / 4); i += 256)
            dstl[i] = (i < maxv) ? src[i] : make_float4(0.f, 0.f, 0.f, 0.f);
    }

    const int c  = tid & (D - 1);   // column 0..127
    const int rg = tid >> 7;        // row group 0..1 (8 rows each)

    float acc[8];
#pragma unroll
    for (int j = 0; j < 8; ++j) acc[j] = 0.0f;

    for (int kk = 0; kk < D; kk += 64) {
        __syncthreads();            // A staged (1st pass) / Wl free (2nd pass)
        // Stage W rows kk..kk+63 (contiguous 32 KB copy, float4).
        {
            const float4* wsrc = (const float4*)(W + kk * D);
            float4*       wdst = (float4*)&Wl[0][0];
            for (int i = tid; i < 64 * (D / 4); i += 256) wdst[i] = wsrc[i];
        }
        __syncthreads();
#pragma unroll 4
        for (int k = 0; k < 64; ++k) {
            float wv = Wl[k][c];
#pragma unroll
            for (int j = 0; j < 8; ++j)
                acc[j] += Al[rg * 8 + j][kk + k] * wv;
        }
    }

    // Epilogue: divide by clamped degree, add gated bias, relu, store.
    const float bc = b[c];
#pragma unroll
    for (int j = 0; j < 8; ++j) {
        int r = row0 + rg * 8 + j;
        if (r < n_dst) {
            float d  = deg[r];
            float dc = fmaxf(d, 1.0f);
            float v  = acc[j] / dc + (d > 0.0f ? bc : 0.0f);
            out[(size_t)r * D + c] = fmaxf(v, 0.0f);
        }
    }
}

extern "C" void kernel_launch(void* const* d_in, const int* in_sizes, int n_in,
                              void* d_out, int out_size, void* d_ws, size_t ws_size,
                              hipStream_t stream) {
    const float* H    = (const float*)d_in[0];   // [N_src, 128]
    const float* W    = (const float*)d_in[1];   // [128, 128]
    const float* b    = (const float*)d_in[2];   // [128]
    const int*   esrc = (const int*)d_in[3];     // [E]
    const int*   edst = (const int*)d_in[4];     // [E]
    const int    E     = in_sizes[3];
    const int    n_dst = out_size / D;           // n_dst scalar lives on device; derive from out_size

    float* out = (float*)d_out;                  // doubles as agg accumulator
    float* deg = (float*)d_ws;                   // [n_dst] floats

    hipMemsetAsync(d_out, 0, (size_t)out_size * sizeof(float), stream);
    hipMemsetAsync(d_ws, 0, (size_t)n_dst * sizeof(float), stream);

    scatter_kernel<<<(E + 7) / 8, 256, 0, stream>>>(H, esrc, edst, out, deg, E);
    gemm_finalize_kernel<<<(n_dst + 15) / 16, 256, 0, stream>>>(out, W, b, deg, n_dst);
}

// Round 2
// 305.966 us; speedup vs baseline: 3.8655x; 3.8655x over previous
//
#include <hip/hip_runtime.h>

#define D 128

// ---------------------------------------------------------------------------
// Stage 1: histogram of edge destinations (int atomics, avg 12/counter).
// ---------------------------------------------------------------------------
__global__ __launch_bounds__(256) void hist_kernel(
    const int* __restrict__ edst, int* __restrict__ counts, int E)
{
    int e = blockIdx.x * 256 + threadIdx.x;
    if (e < E) atomicAdd(&counts[edst[e]], 1);
}

// ---------------------------------------------------------------------------
// Stage 2: exclusive scan of counts -> offsets[n+1]. Single 1024-thread block,
// wave-shuffle scan (6 steps) + cross-wave LDS scan. ~49 tiles for n=50000.
// ---------------------------------------------------------------------------
__global__ __launch_bounds__(1024) void scan_kernel(
    const int* __restrict__ counts, int* __restrict__ offsets, int n)
{
    __shared__ int wsum[16];
    __shared__ int carry_s;
    const int tid = threadIdx.x;
    const int lane = tid & 63, wv = tid >> 6;
    if (tid == 0) { carry_s = 0; offsets[0] = 0; }
    __syncthreads();
    for (int base = 0; base < n; base += 1024) {
        int i = base + tid;
        int x = (i < n) ? counts[i] : 0;
#pragma unroll
        for (int off = 1; off < 64; off <<= 1) {
            int t = __shfl_up(x, off, 64);
            if (lane >= off) x += t;
        }
        if (lane == 63) wsum[wv] = x;
        __syncthreads();
        if (wv == 0) {
            int s = (lane < 16) ? wsum[lane] : 0;
#pragma unroll
            for (int off = 1; off < 16; off <<= 1) {
                int t = __shfl_up(s, off, 64);
                if (lane >= off) s += t;
            }
            if (lane < 16) wsum[lane] = s;   // inclusive per-wave sums
        }
        __syncthreads();
        int waveoff = (wv == 0) ? 0 : wsum[wv - 1];
        if (i < n) offsets[i + 1] = carry_s + waveoff + x;
        __syncthreads();
        if (tid == 0) carry_s += wsum[15];
        __syncthreads();
    }
}

// ---------------------------------------------------------------------------
// Stage 3: counting-sort scatter of edge sources into CSR order.
// ---------------------------------------------------------------------------
__global__ __launch_bounds__(256) void sort_kernel(
    const int* __restrict__ esrc, const int* __restrict__ edst,
    const int* __restrict__ offsets, int* __restrict__ cursors,
    int* __restrict__ sorted_src, int E)
{
    int e = blockIdx.x * 256 + threadIdx.x;
    if (e < E) {
        int d = edst[e];
        int pos = offsets[d] + atomicAdd(&cursors[d], 1);
        sorted_src[pos] = esrc[e];
    }
}

// ---------------------------------------------------------------------------
// Stage 4: pull aggregation. One wave per dst row; lane holds 2 columns
// (float2 -> 512 B coalesced per H row per wave). Edge loop unrolled x2 for
// MLP. Every output row written exactly once -> no atomics, no memset.
// ---------------------------------------------------------------------------
__global__ __launch_bounds__(256) void aggregate_kernel(
    const float* __restrict__ H, const int* __restrict__ sorted_src,
    const int* __restrict__ offsets, float* __restrict__ agg, int n_dst)
{
    int dst = blockIdx.x * 4 + (threadIdx.x >> 6);
    if (dst >= n_dst) return;
    int lane = threadIdx.x & 63;
    int beg = offsets[dst], end = offsets[dst + 1];
    float2 a0 = make_float2(0.f, 0.f), a1 = make_float2(0.f, 0.f);
    int i = beg;
    for (; i + 1 < end; i += 2) {
        int s0 = sorted_src[i], s1 = sorted_src[i + 1];
        float2 v0 = ((const float2*)(H + (size_t)s0 * D))[lane];
        float2 v1 = ((const float2*)(H + (size_t)s1 * D))[lane];
        a0.x += v0.x; a0.y += v0.y;
        a1.x += v1.x; a1.y += v1.y;
    }
    if (i < end) {
        int s0 = sorted_src[i];
        float2 v0 = ((const float2*)(H + (size_t)s0 * D))[lane];
        a0.x += v0.x; a0.y += v0.y;
    }
    ((float2*)(agg + (size_t)dst * D))[lane] =
        make_float2(a0.x + a1.x, a0.y + a1.y);
}

// ---------------------------------------------------------------------------
// Stage 5: out = relu( (agg @ W) / max(deg,1) + (deg>0 ? b : 0) ), in-place.
// deg derived from CSR offsets. Block = 16 rows; A fully LDS-staged before
// any global write (in-place safe). LDS = 40 KB -> 4 blocks/CU.
// ---------------------------------------------------------------------------
__global__ __launch_bounds__(256) void gemm_finalize_kernel(
    float* __restrict__ out, const float* __restrict__ W,
    const float* __restrict__ b, const int* __restrict__ offsets, int n_dst)
{
    __shared__ float Wl[64][D];   // 32 KB: half of W (64 k-rows)
    __shared__ float Al[16][D];   // 8 KB: 16 A rows

    const int tid  = threadIdx.x;
    const int row0 = blockIdx.x * 16;

    {
        const float4* src  = (const float4*)(out + (size_t)row0 * D);
        float4*       dstl = (float4*)&Al[0][0];
        int maxv = (n_dst - row0) * (D / 4);
        if (maxv > 16 * (D / 4)) maxv = 16 * (D / 4);
        for (int i = tid; i < 16 * (D / 4); i += 256)
            dstl[i] = (i < maxv) ? src[i] : make_float4(0.f, 0.f, 0.f, 0.f);
    }

    const int c  = tid & (D - 1);
    const int rg = tid >> 7;

    float acc[8];
#pragma unroll
    for (int j = 0; j < 8; ++j) acc[j] = 0.0f;

    for (int kk = 0; kk < D; kk += 64) {
        __syncthreads();
        {
            const float4* wsrc = (const float4*)(W + kk * D);
            float4*       wdst = (float4*)&Wl[0][0];
            for (int i = tid; i < 64 * (D / 4); i += 256) wdst[i] = wsrc[i];
        }
        __syncthreads();
#pragma unroll 4
        for (int k = 0; k < 64; ++k) {
            float wv = Wl[k][c];
#pragma unroll
            for (int j = 0; j < 8; ++j)
                acc[j] += Al[rg * 8 + j][kk + k] * wv;
        }
    }

    const float bc = b[c];
#pragma unroll
    for (int j = 0; j < 8; ++j) {
        int r = row0 + rg * 8 + j;
        if (r < n_dst) {
            int   dg = offsets[r + 1] - offsets[r];
            float dc = (float)(dg > 1 ? dg : 1);
            float v  = acc[j] / dc + (dg > 0 ? bc : 0.0f);
            out[(size_t)r * D + c] = fmaxf(v, 0.0f);
        }
    }
}

extern "C" void kernel_launch(void* const* d_in, const int* in_sizes, int n_in,
                              void* d_out, int out_size, void* d_ws, size_t ws_size,
                              hipStream_t stream) {
    const float* H    = (const float*)d_in[0];   // [N_src, 128]
    const float* W    = (const float*)d_in[1];   // [128, 128]
    const float* b    = (const float*)d_in[2];   // [128]
    const int*   esrc = (const int*)d_in[3];     // [E]
    const int*   edst = (const int*)d_in[4];     // [E]
    const int    E     = in_sizes[3];
    const int    n_dst = out_size / D;

    float* out = (float*)d_out;                  // doubles as agg accumulator

    // ws layout: [counts n | cursors n | offsets n+1 | sorted_src E]
    int* counts  = (int*)d_ws;
    int* cursors = counts + n_dst;
    int* offsets = cursors + n_dst;
    int* sorted  = offsets + n_dst + 1;

    hipMemsetAsync(d_ws, 0, (size_t)(2 * n_dst) * sizeof(int), stream);

    hist_kernel<<<(E + 255) / 256, 256, 0, stream>>>(edst, counts, E);
    scan_kernel<<<1, 1024, 0, stream>>>(counts, offsets, n_dst);
    sort_kernel<<<(E + 255) / 256, 256, 0, stream>>>(esrc, edst, offsets, cursors, sorted, E);
    aggregate_kernel<<<(n_dst + 3) / 4, 256, 0, stream>>>(H, sorted, offsets, out, n_dst);
    gemm_finalize_kernel<<<(n_dst + 15) / 16, 256, 0, stream>>>(out, W, b, offsets, n_dst);
}

// Round 3
// 250.422 us; speedup vs baseline: 4.7229x; 1.2218x over previous
//
#include <hip/hip_runtime.h>

#define D 128

// ---------------------------------------------------------------------------
// Stage 1: histogram of edge destinations (int atomics, avg 12/counter).
// ---------------------------------------------------------------------------
__global__ __launch_bounds__(256) void hist_kernel(
    const int* __restrict__ edst, int* __restrict__ counts, int E)
{
    int e = blockIdx.x * 256 + threadIdx.x;
    if (e < E) atomicAdd(&counts[edst[e]], 1);
}

// ---------------------------------------------------------------------------
// Stage 2a: per-tile (1024-elem) block-inclusive scan. Writes block-local
// inclusive scan into offsets[i+1] and the tile total into tilesums[blk].
// ---------------------------------------------------------------------------
__global__ __launch_bounds__(1024) void scan_tile_kernel(
    const int* __restrict__ counts, int* __restrict__ offsets,
    int* __restrict__ tilesums, int n)
{
    __shared__ int wsum[16];
    const int tid = threadIdx.x;
    const int lane = tid & 63, wv = tid >> 6;
    int i = blockIdx.x * 1024 + tid;
    int x = (i < n) ? counts[i] : 0;
#pragma unroll
    for (int off = 1; off < 64; off <<= 1) {
        int t = __shfl_up(x, off, 64);
        if (lane >= off) x += t;
    }
    if (lane == 63) wsum[wv] = x;
    __syncthreads();
    if (wv == 0 && lane < 16) {
        int s = wsum[lane];
#pragma unroll
        for (int off = 1; off < 16; off <<= 1) {
            int t = __shfl_up(s, off, 64);
            if (lane >= off) s += t;
        }
        wsum[lane] = s;
    }
    __syncthreads();
    int waveoff = (wv == 0) ? 0 : wsum[wv - 1];
    if (i < n) offsets[i + 1] = waveoff + x;
    if (tid == 0) tilesums[blockIdx.x] = wsum[15];
}

// ---------------------------------------------------------------------------
// Stage 2b: exclusive scan of tile sums in place (1 block, ntiles <= 1024).
// ---------------------------------------------------------------------------
__global__ __launch_bounds__(1024) void scan_sums_kernel(
    int* __restrict__ tilesums, int ntiles)
{
    __shared__ int wsum[16];
    const int tid = threadIdx.x;
    const int lane = tid & 63, wv = tid >> 6;
    int x0 = (tid < ntiles) ? tilesums[tid] : 0;
    int x = x0;
#pragma unroll
    for (int off = 1; off < 64; off <<= 1) {
        int t = __shfl_up(x, off, 64);
        if (lane >= off) x += t;
    }
    if (lane == 63) wsum[wv] = x;
    __syncthreads();
    if (wv == 0 && lane < 16) {
        int s = wsum[lane];
#pragma unroll
        for (int off = 1; off < 16; off <<= 1) {
            int t = __shfl_up(s, off, 64);
            if (lane >= off) s += t;
        }
        wsum[lane] = s;
    }
    __syncthreads();
    int waveoff = (wv == 0) ? 0 : wsum[wv - 1];
    if (tid < ntiles) tilesums[tid] = waveoff + x - x0;   // exclusive
}

// ---------------------------------------------------------------------------
// Stage 2c: add tile prefixes back; set offsets[0] = 0.
// ---------------------------------------------------------------------------
__global__ __launch_bounds__(1024) void scan_fixup_kernel(
    int* __restrict__ offsets, const int* __restrict__ tilesums, int n)
{
    int i = blockIdx.x * 1024 + threadIdx.x;
    if (i < n) offsets[i + 1] += tilesums[blockIdx.x];
    if (i == 0) offsets[0] = 0;
}

// ---------------------------------------------------------------------------
// Stage 3: counting-sort scatter of edge sources into CSR order.
// ---------------------------------------------------------------------------
__global__ __launch_bounds__(256) void sort_kernel(
    const int* __restrict__ esrc, const int* __restrict__ edst,
    const int* __restrict__ offsets, int* __restrict__ cursors,
    int* __restrict__ sorted_src, int E)
{
    int e = blockIdx.x * 256 + threadIdx.x;
    if (e < E) {
        int d = edst[e];
        int pos = offsets[d] + atomicAdd(&cursors[d], 1);
        sorted_src[pos] = esrc[e];
    }
}

// ---------------------------------------------------------------------------
// Stage 4: pull aggregation. One wave per dst row; lane holds 2 columns.
// Edge indices prefetched 64-at-a-time via a single coalesced lane-load and
// broadcast with __shfl (index loads off the gather critical path); gather
// unrolled x4 -> 4 independent global_load_dwordx2 in flight per wave.
// ---------------------------------------------------------------------------
__global__ __launch_bounds__(256) void aggregate_kernel(
    const float* __restrict__ H, const int* __restrict__ sorted_src,
    const int* __restrict__ offsets, float* __restrict__ agg, int n_dst)
{
    int dst = blockIdx.x * 4 + (threadIdx.x >> 6);
    if (dst >= n_dst) return;
    int lane = threadIdx.x & 63;
    int beg = offsets[dst], end = offsets[dst + 1];
    const float2* Hv = (const float2*)H;

    float ax0 = 0.f, ay0 = 0.f, ax1 = 0.f, ay1 = 0.f;
    for (int chunk = beg; chunk < end; chunk += 64) {
        int m = end - chunk;
        if (m > 64) m = 64;
        int idx = (lane < m) ? sorted_src[chunk + lane] : 0;
        int j = 0;
        for (; j + 4 <= m; j += 4) {
            int s0 = __shfl(idx, j + 0);
            int s1 = __shfl(idx, j + 1);
            int s2 = __shfl(idx, j + 2);
            int s3 = __shfl(idx, j + 3);
            float2 v0 = Hv[(size_t)s0 * (D / 2) + lane];
            float2 v1 = Hv[(size_t)s1 * (D / 2) + lane];
            float2 v2 = Hv[(size_t)s2 * (D / 2) + lane];
            float2 v3 = Hv[(size_t)s3 * (D / 2) + lane];
            ax0 += v0.x + v1.x; ay0 += v0.y + v1.y;
            ax1 += v2.x + v3.x; ay1 += v2.y + v3.y;
        }
        for (; j < m; ++j) {
            int s0 = __shfl(idx, j);
            float2 v0 = Hv[(size_t)s0 * (D / 2) + lane];
            ax0 += v0.x; ay0 += v0.y;
        }
    }
    ((float2*)(agg + (size_t)dst * D))[lane] = make_float2(ax0 + ax1, ay0 + ay1);
}

// ---------------------------------------------------------------------------
// Stage 5: out = relu( (agg @ W) / max(deg,1) + (deg>0 ? b : 0) ), in-place.
// deg derived from CSR offsets. Block = 16 rows; A fully LDS-staged before
// any global write (in-place safe). LDS = 40 KB -> 4 blocks/CU.
// ---------------------------------------------------------------------------
__global__ __launch_bounds__(256) void gemm_finalize_kernel(
    float* __restrict__ out, const float* __restrict__ W,
    const float* __restrict__ b, const int* __restrict__ offsets, int n_dst)
{
    __shared__ float Wl[64][D];   // 32 KB: half of W (64 k-rows)
    __shared__ float Al[16][D];   // 8 KB: 16 A rows

    const int tid  = threadIdx.x;
    const int row0 = blockIdx.x * 16;

    {
        const float4* src  = (const float4*)(out + (size_t)row0 * D);
        float4*       dstl = (float4*)&Al[0][0];
        int maxv = (n_dst - row0) * (D / 4);
        if (maxv > 16 * (D / 4)) maxv = 16 * (D / 4);
        for (int i = tid; i < 16 * (D / 4); i += 256)
            dstl[i] = (i < maxv) ? src[i] : make_float4(0.f, 0.f, 0.f, 0.f);
    }

    const int c  = tid & (D - 1);
    const int rg = tid >> 7;

    float acc[8];
#pragma unroll
    for (int j = 0; j < 8; ++j) acc[j] = 0.0f;

    for (int kk = 0; kk < D; kk += 64) {
        __syncthreads();
        {
            const float4* wsrc = (const float4*)(W + kk * D);
            float4*       wdst = (float4*)&Wl[0][0];
            for (int i = tid; i < 64 * (D / 4); i += 256) wdst[i] = wsrc[i];
        }
        __syncthreads();
#pragma unroll 4
        for (int k = 0; k < 64; ++k) {
            float wv = Wl[k][c];
#pragma unroll
            for (int j = 0; j < 8; ++j)
                acc[j] += Al[rg * 8 + j][kk + k] * wv;
        }
    }

    const float bc = b[c];
#pragma unroll
    for (int j = 0; j < 8; ++j) {
        int r = row0 + rg * 8 + j;
        if (r < n_dst) {
            int   dg = offsets[r + 1] - offsets[r];
            float dc = (float)(dg > 1 ? dg : 1);
            float v  = acc[j] / dc + (dg > 0 ? bc : 0.0f);
            out[(size_t)r * D + c] = fmaxf(v, 0.0f);
        }
    }
}

extern "C" void kernel_launch(void* const* d_in, const int* in_sizes, int n_in,
                              void* d_out, int out_size, void* d_ws, size_t ws_size,
                              hipStream_t stream) {
    const float* H    = (const float*)d_in[0];   // [N_src, 128]
    const float* W    = (const float*)d_in[1];   // [128, 128]
    const float* b    = (const float*)d_in[2];   // [128]
    const int*   esrc = (const int*)d_in[3];     // [E]
    const int*   edst = (const int*)d_in[4];     // [E]
    const int    E     = in_sizes[3];
    const int    n_dst = out_size / D;

    float* out = (float*)d_out;                  // doubles as agg accumulator

    const int ntiles = (n_dst + 1023) / 1024;

    // ws layout: [counts n | cursors n | offsets n+1 | tilesums ntiles | sorted_src E]
    int* counts   = (int*)d_ws;
    int* cursors  = counts + n_dst;
    int* offsets  = cursors + n_dst;
    int* tilesums = offsets + n_dst + 1;
    int* sorted   = tilesums + ntiles;

    hipMemsetAsync(d_ws, 0, (size_t)(2 * n_dst) * sizeof(int), stream);

    hist_kernel<<<(E + 255) / 256, 256, 0, stream>>>(edst, counts, E);
    scan_tile_kernel<<<ntiles, 1024, 0, stream>>>(counts, offsets, tilesums, n_dst);
    scan_sums_kernel<<<1, 1024, 0, stream>>>(tilesums, ntiles);
    scan_fixup_kernel<<<ntiles, 1024, 0, stream>>>(offsets, tilesums, n_dst);
    sort_kernel<<<(E + 255) / 256, 256, 0, stream>>>(esrc, edst, offsets, cursors, sorted, E);
    aggregate_kernel<<<(n_dst + 3) / 4, 256, 0, stream>>>(H, sorted, offsets, out, n_dst);
    gemm_finalize_kernel<<<(n_dst + 15) / 16, 256, 0, stream>>>(out, W, b, offsets, n_dst);
}

// Round 4
// 216.467 us; speedup vs baseline: 5.4637x; 1.1569x over previous
//
#include <hip/hip_runtime.h>

#define D 128
#define LDA 136   // bf16 elems per LDS row (+8 pad -> 2-way bank conflicts only)

typedef __attribute__((ext_vector_type(8))) short bf16x8;
typedef __attribute__((ext_vector_type(4))) float f32x4;

static __device__ __forceinline__ unsigned short f2bf(float f) {
    unsigned u = __float_as_uint(f);
    unsigned r = 0x7fffu + ((u >> 16) & 1u);   // round-to-nearest-even
    return (unsigned short)((u + r) >> 16);
}

// ---------------------------------------------------------------------------
// Stage 0: W [k][n] fp32 -> Wt [n][k] bf16 (once; 16384 elems).
// ---------------------------------------------------------------------------
__global__ __launch_bounds__(256) void wt_kernel(
    const float* __restrict__ W, unsigned short* __restrict__ Wt)
{
    int idx = blockIdx.x * 256 + threadIdx.x;   // 0..16383
    int k = idx >> 7, n = idx & 127;
    Wt[n * 128 + k] = f2bf(W[idx]);
}

// ---------------------------------------------------------------------------
// Stage 1: histogram of edge destinations.
// ---------------------------------------------------------------------------
__global__ __launch_bounds__(256) void hist_kernel(
    const int* __restrict__ edst, int* __restrict__ counts, int E)
{
    int e = blockIdx.x * 256 + threadIdx.x;
    if (e < E) atomicAdd(&counts[edst[e]], 1);
}

// ---------------------------------------------------------------------------
// Stage 2a: per-tile (1024) block-inclusive scan -> offsets[i+1], tilesums.
// ---------------------------------------------------------------------------
__global__ __launch_bounds__(1024) void scan_tile_kernel(
    const int* __restrict__ counts, int* __restrict__ offsets,
    int* __restrict__ tilesums, int n)
{
    __shared__ int wsum[16];
    const int tid = threadIdx.x;
    const int lane = tid & 63, wv = tid >> 6;
    int i = blockIdx.x * 1024 + tid;
    int x = (i < n) ? counts[i] : 0;
#pragma unroll
    for (int off = 1; off < 64; off <<= 1) {
        int t = __shfl_up(x, off, 64);
        if (lane >= off) x += t;
    }
    if (lane == 63) wsum[wv] = x;
    __syncthreads();
    if (wv == 0 && lane < 16) {
        int s = wsum[lane];
#pragma unroll
        for (int off = 1; off < 16; off <<= 1) {
            int t = __shfl_up(s, off, 64);
            if (lane >= off) s += t;
        }
        wsum[lane] = s;
    }
    __syncthreads();
    int waveoff = (wv == 0) ? 0 : wsum[wv - 1];
    if (i < n) offsets[i + 1] = waveoff + x;
    if (tid == 0) tilesums[blockIdx.x] = wsum[15];
}

// ---------------------------------------------------------------------------
// Stage 2b: exclusive scan of tile sums in place (1 block, ntiles <= 1024).
// ---------------------------------------------------------------------------
__global__ __launch_bounds__(1024) void scan_sums_kernel(
    int* __restrict__ tilesums, int ntiles)
{
    __shared__ int wsum[16];
    const int tid = threadIdx.x;
    const int lane = tid & 63, wv = tid >> 6;
    int x0 = (tid < ntiles) ? tilesums[tid] : 0;
    int x = x0;
#pragma unroll
    for (int off = 1; off < 64; off <<= 1) {
        int t = __shfl_up(x, off, 64);
        if (lane >= off) x += t;
    }
    if (lane == 63) wsum[wv] = x;
    __syncthreads();
    if (wv == 0 && lane < 16) {
        int s = wsum[lane];
#pragma unroll
        for (int off = 1; off < 16; off <<= 1) {
            int t = __shfl_up(s, off, 64);
            if (lane >= off) s += t;
        }
        wsum[lane] = s;
    }
    __syncthreads();
    int waveoff = (wv == 0) ? 0 : wsum[wv - 1];
    if (tid < ntiles) tilesums[tid] = waveoff + x - x0;   // exclusive
}

// ---------------------------------------------------------------------------
// Stage 2c: add tile prefixes back; offsets[0] = 0.
// ---------------------------------------------------------------------------
__global__ __launch_bounds__(1024) void scan_fixup_kernel(
    int* __restrict__ offsets, const int* __restrict__ tilesums, int n)
{
    int i = blockIdx.x * 1024 + threadIdx.x;
    if (i < n) offsets[i + 1] += tilesums[blockIdx.x];
    if (i == 0) offsets[0] = 0;
}

// ---------------------------------------------------------------------------
// Stage 3: counting-sort scatter of edge sources into CSR order.
// ---------------------------------------------------------------------------
__global__ __launch_bounds__(256) void sort_kernel(
    const int* __restrict__ esrc, const int* __restrict__ edst,
    const int* __restrict__ offsets, int* __restrict__ cursors,
    int* __restrict__ sorted_src, int E)
{
    int e = blockIdx.x * 256 + threadIdx.x;
    if (e < E) {
        int d = edst[e];
        int pos = offsets[d] + atomicAdd(&cursors[d], 1);
        sorted_src[pos] = esrc[e];
    }
}

// ---------------------------------------------------------------------------
// Stage 4: pull aggregation (one wave per dst row; 64-edge index prefetch +
// __shfl broadcast; gather unrolled x4).
// ---------------------------------------------------------------------------
__global__ __launch_bounds__(256) void aggregate_kernel(
    const float* __restrict__ H, const int* __restrict__ sorted_src,
    const int* __restrict__ offsets, float* __restrict__ agg, int n_dst)
{
    int dst = blockIdx.x * 4 + (threadIdx.x >> 6);
    if (dst >= n_dst) return;
    int lane = threadIdx.x & 63;
    int beg = offsets[dst], end = offsets[dst + 1];
    const float2* Hv = (const float2*)H;

    float ax0 = 0.f, ay0 = 0.f, ax1 = 0.f, ay1 = 0.f;
    for (int chunk = beg; chunk < end; chunk += 64) {
        int m = end - chunk;
        if (m > 64) m = 64;
        int idx = (lane < m) ? sorted_src[chunk + lane] : 0;
        int j = 0;
        for (; j + 4 <= m; j += 4) {
            int s0 = __shfl(idx, j + 0);
            int s1 = __shfl(idx, j + 1);
            int s2 = __shfl(idx, j + 2);
            int s3 = __shfl(idx, j + 3);
            float2 v0 = Hv[(size_t)s0 * (D / 2) + lane];
            float2 v1 = Hv[(size_t)s1 * (D / 2) + lane];
            float2 v2 = Hv[(size_t)s2 * (D / 2) + lane];
            float2 v3 = Hv[(size_t)s3 * (D / 2) + lane];
            ax0 += v0.x + v1.x; ay0 += v0.y + v1.y;
            ax1 += v2.x + v3.x; ay1 += v2.y + v3.y;
        }
        for (; j < m; ++j) {
            int s0 = __shfl(idx, j);
            float2 v0 = Hv[(size_t)s0 * (D / 2) + lane];
            ax0 += v0.x; ay0 += v0.y;
        }
    }
    ((float2*)(agg + (size_t)dst * D))[lane] = make_float2(ax0 + ax1, ay0 + ay1);
}

// ---------------------------------------------------------------------------
// Stage 5: out = relu( (agg @ W) / max(deg,1) + (deg>0 ? b : 0) ) via bf16
// MFMA, in-place on d_out. Block = 4 waves, 64 rows; wave w owns rows
// [16w,16w+16) x all 128 cols = 8 accumulator tiles, 32 mfma_16x16x32_bf16.
// A/Wt staged bf16 in LDS (stride 136 -> 2-way conflicts = free). Epilogue
// round-trips C through LDS for coalesced float4 stores. In-place safe:
// rows block-exclusive, A fully staged before any global write.
// ---------------------------------------------------------------------------
__global__ __launch_bounds__(256) void gemm_finalize_kernel(
    float* __restrict__ out, const unsigned short* __restrict__ Wt,
    const float* __restrict__ b, const int* __restrict__ offsets, int n_dst)
{
    __shared__ __align__(16) unsigned char smem[52224];
    unsigned short* Ash = (unsigned short*)smem;            // [64][LDA]
    unsigned short* Wsh = (unsigned short*)(smem + 64 * LDA * 2); // [128][LDA]
    float* Csh = (float*)smem;                              // [64][132] (reuse)

    const int tid  = threadIdx.x;
    const size_t row0 = (size_t)blockIdx.x * 64;

    // Stage A: 64 rows x 128 fp32 -> bf16 LDS (2048 float4, coalesced).
#pragma unroll
    for (int t = 0; t < 8; ++t) {
        int i = tid + t * 256;
        int r = i >> 5;                 // row 0..63
        int c4 = i & 31;                // float4 idx in row
        size_t gr = row0 + r;
        float4 v = (gr < (size_t)n_dst) ? ((const float4*)out)[gr * (D / 4) + c4]
                                        : make_float4(0.f, 0.f, 0.f, 0.f);
        unsigned p01 = (unsigned)f2bf(v.x) | ((unsigned)f2bf(v.y) << 16);
        unsigned p23 = (unsigned)f2bf(v.z) | ((unsigned)f2bf(v.w) << 16);
        *(uint2*)&Ash[r * LDA + c4 * 4] = make_uint2(p01, p23);
    }
    // Stage Wt: 128 rows x 128 bf16 (2048 uint4, coalesced).
#pragma unroll
    for (int t = 0; t < 8; ++t) {
        int i = tid + t * 256;
        int n  = i >> 4;                // row 0..127
        int k8 = (i & 15) << 3;         // k start
        uint4 w = ((const uint4*)Wt)[i];
        *(uint4*)&Wsh[n * LDA + k8] = w;
    }
    __syncthreads();

    const int lane = tid & 63;
    const int wv   = tid >> 6;          // m-tile 0..3
    const int m0   = wv * 16;
    const int hl   = lane & 15;         // A row within tile / B col
    const int quad = lane >> 4;

    f32x4 acc[8];
#pragma unroll
    for (int n = 0; n < 8; ++n) acc[n] = (f32x4){0.f, 0.f, 0.f, 0.f};

#pragma unroll
    for (int kc = 0; kc < 128; kc += 32) {
        bf16x8 a = *(const bf16x8*)&Ash[(m0 + hl) * LDA + kc + quad * 8];
#pragma unroll
        for (int n = 0; n < 8; ++n) {
            bf16x8 bf = *(const bf16x8*)&Wsh[(n * 16 + hl) * LDA + kc + quad * 8];
            acc[n] = __builtin_amdgcn_mfma_f32_16x16x32_bf16(a, bf, acc[n], 0, 0, 0);
        }
    }

    // Per-lane degree info for its 4 C rows (row = quad*4 + r within tile).
    float inv[4], gate[4];
#pragma unroll
    for (int r = 0; r < 4; ++r) {
        size_t gr = row0 + m0 + quad * 4 + r;
        int dg = (gr < (size_t)n_dst) ? offsets[gr + 1] - offsets[gr] : 0;
        inv[r]  = 1.0f / (float)(dg > 1 ? dg : 1);
        gate[r] = (dg > 0) ? 1.0f : 0.0f;
    }
    __syncthreads();   // A/Wt dead; reuse LDS as Csh

    // Epilogue into Csh [64][132] (stride pad -> 2-way write conflicts only).
#pragma unroll
    for (int n = 0; n < 8; ++n) {
        int col = n * 16 + hl;
        float bc = b[col];
#pragma unroll
        for (int r = 0; r < 4; ++r) {
            float v = acc[n][r] * inv[r] + bc * gate[r];
            Csh[(m0 + quad * 4 + r) * 132 + col] = fmaxf(v, 0.0f);
        }
    }
    __syncthreads();

    // Coalesced float4 store.
#pragma unroll
    for (int t = 0; t < 8; ++t) {
        int i = tid + t * 256;
        int r = i >> 5;
        int c4 = i & 31;
        size_t gr = row0 + r;
        if (gr < (size_t)n_dst) {
            float4 v = *(float4*)&Csh[r * 132 + c4 * 4];
            ((float4*)out)[gr * (D / 4) + c4] = v;
        }
    }
}

extern "C" void kernel_launch(void* const* d_in, const int* in_sizes, int n_in,
                              void* d_out, int out_size, void* d_ws, size_t ws_size,
                              hipStream_t stream) {
    const float* H    = (const float*)d_in[0];   // [N_src, 128]
    const float* W    = (const float*)d_in[1];   // [128, 128]
    const float* b    = (const float*)d_in[2];   // [128]
    const int*   esrc = (const int*)d_in[3];     // [E]
    const int*   edst = (const int*)d_in[4];     // [E]
    const int    E     = in_sizes[3];
    const int    n_dst = out_size / D;

    float* out = (float*)d_out;                  // doubles as agg accumulator

    const int ntiles = (n_dst + 1023) / 1024;

    // ws layout: [Wt bf16 128x128 (32KB)] [counts n | cursors n | offsets n+1
    //             | tilesums ntiles | sorted_src E]
    unsigned short* Wt = (unsigned short*)d_ws;
    int* counts   = (int*)((char*)d_ws + 128 * 128 * sizeof(unsigned short));
    int* cursors  = counts + n_dst;
    int* offsets  = cursors + n_dst;
    int* tilesums = offsets + n_dst + 1;
    int* sorted   = tilesums + ntiles;

    hipMemsetAsync(counts, 0, (size_t)(2 * n_dst) * sizeof(int), stream);

    wt_kernel<<<64, 256, 0, stream>>>(W, Wt);
    hist_kernel<<<(E + 255) / 256, 256, 0, stream>>>(edst, counts, E);
    scan_tile_kernel<<<ntiles, 1024, 0, stream>>>(counts, offsets, tilesums, n_dst);
    scan_sums_kernel<<<1, 1024, 0, stream>>>(tilesums, ntiles);
    scan_fixup_kernel<<<ntiles, 1024, 0, stream>>>(offsets, tilesums, n_dst);
    sort_kernel<<<(E + 255) / 256, 256, 0, stream>>>(esrc, edst, offsets, cursors, sorted, E);
    aggregate_kernel<<<(n_dst + 3) / 4, 256, 0, stream>>>(H, sorted, offsets, out, n_dst);
    gemm_finalize_kernel<<<(n_dst + 63) / 64, 256, 0, stream>>>(out, Wt, b, offsets, n_dst);
}